// Round 3
// baseline (1234.520 us; speedup 1.0000x reference)
//
#include <hip/hip_runtime.h>
#include <hip/hip_bf16.h>

#define NN 8192
#define KF 256
#define KD 512
#define CK 32

typedef unsigned int uint32;
typedef unsigned short ushort16;

static __device__ __forceinline__ float bf2f(ushort16 u) {
    union { uint32 i; float f; } v; v.i = ((uint32)u) << 16; return v.f;
}
static __device__ __forceinline__ ushort16 f2bf(float f) {
    __hip_bfloat16 h = __float2bfloat16(f);  // RNE
    union { __hip_bfloat16 h; ushort16 u; } v; v.h = h; return v.u;
}

// ---------------- K-1: detect input dtype ----------------
__global__ void detect_kernel(const uint32* __restrict__ rawA, int* __restrict__ flag) {
    __shared__ int s_top2, s_nz;
    if (threadIdx.x == 0) { s_top2 = 0; s_nz = 0; }
    __syncthreads();
    int top2 = 0, nz = 0;
    for (int i = threadIdx.x; i < 4096; i += 256) {
        uint32 lo = rawA[i] & 0xFFFFu;
        if (lo & 0xC000u) top2 = 1;
        if (lo) nz = 1;
    }
    if (top2) atomicOr(&s_top2, 1);
    if (nz) atomicOr(&s_nz, 1);
    __syncthreads();
    if (threadIdx.x == 0) {
        int f;
        if (s_top2) f = 1;        // true fp32
        else if (s_nz) f = 0;     // bf16 storage
        else f = 1;               // fp32 holding bf16-rounded values
        *flag = f;
    }
}

// ---------------- K0: zero accumulators ----------------
__global__ void init_kernel(double* acc, double* gstats) {
    int i = blockIdx.x * 256 + threadIdx.x;
    if (i < 4 * NN) acc[i] = 0.0;
    if (i < 2) gstats[i] = 0.0;
}

// ---------------- K1: top-32 mask + build X = [Ac | As] (fp32) + sq ----------------
__global__ void prep_kernel(const void* __restrict__ P_, const void* __restrict__ A_,
                            const int* __restrict__ flag,
                            float* __restrict__ X, float* __restrict__ sq) {
    int f = *flag;
    int row = blockIdx.x * 4 + (threadIdx.x >> 6);
    int lane = threadIdx.x & 63;
    if (row >= NN) return;
    float a[4], p[4];
    bool sel[4] = {false, false, false, false};
    if (f) {
        const float* Ar = (const float*)A_ + (size_t)row * KF;
        const float* Pr = (const float*)P_ + (size_t)row * KF;
#pragma unroll
        for (int j = 0; j < 4; j++) {
            int k = lane + 64 * j;
            a[j] = Ar[k];
            p[j] = Pr[k];
        }
    } else {
        const __hip_bfloat16* Ar = (const __hip_bfloat16*)A_ + (size_t)row * KF;
        const __hip_bfloat16* Pr = (const __hip_bfloat16*)P_ + (size_t)row * KF;
#pragma unroll
        for (int j = 0; j < 4; j++) {
            int k = lane + 64 * j;
            a[j] = __bfloat162float(Ar[k]);
            p[j] = __bfloat162float(Pr[k]);
        }
    }
    for (int it = 0; it < CK; ++it) {
        float bv = -1.0f; int bi = KF;
#pragma unroll
        for (int j = 0; j < 4; j++) {
            int k = lane + 64 * j;
            if (!sel[j] && (a[j] > bv || (a[j] == bv && k < bi))) { bv = a[j]; bi = k; }
        }
        for (int off = 32; off > 0; off >>= 1) {
            float ov = __shfl_xor(bv, off);
            int   oi = __shfl_xor(bi, off);
            if (ov > bv || (ov == bv && oi < bi)) { bv = ov; bi = oi; }
        }
        if ((bi & 63) == lane) sel[bi >> 6] = true;
    }
    double sq_part = 0.0;
    float* Xr = X + (size_t)row * KD;
#pragma unroll
    for (int j = 0; j < 4; j++) {
        int k = lane + 64 * j;
        float c = 0.0f, s = 0.0f;
        if (sel[j]) {
            c = a[j] * cosf(p[j]);
            s = a[j] * sinf(p[j]);
            sq_part += (double)a[j] * (double)a[j];
        }
        Xr[k] = c;
        Xr[KF + k] = s;
    }
    for (int off = 32; off > 0; off >>= 1) sq_part += __shfl_xor(sq_part, off);
    if (lane == 0) sq[row] = (float)sq_part;
}

// ---------------- K2: symmetric fp32 GEMM, 128x128 tile, 128 thr, TM16xTN8 ----------------
#define BM 128
#define BN 128
#define BK 16
#define TM 16
#define TN 8
#define LDP 140   // swizzled physical row length: sw(127)=139 -> 140

static __device__ __forceinline__ int sw(int c) { return c + ((c >> 5) << 2); }

__global__ __launch_bounds__(128, 2)
void gemm_kernel(const float* __restrict__ X, const float* __restrict__ sq,
                 void* __restrict__ outv, const int* __restrict__ flag,
                 double* __restrict__ rowsum, double* __restrict__ possum,
                 double* __restrict__ poscnt, double* __restrict__ negcnt) {
    int bx = blockIdx.x, by = blockIdx.y;
    if (bx < by) return;                    // upper-triangle tiles only
    __shared__ float As[BK][LDP];
    __shared__ float Bs[BK][LDP];
    __shared__ double scratch[2][4][BN];
    int f = *flag;
    int tid = threadIdx.x;
    int tx = tid & 15;        // col group (TN=8 cols each)
    int ty = tid >> 4;        // row group (TM=16 rows each)
    int row0 = by * BM, col0 = bx * BN;

    float acc[TM][TN] = {};

    int stid = sw(tid);
    const float* Arow = X + (size_t)(row0 + tid) * KD;
    const float* Brow = X + (size_t)(col0 + tid) * KD;
    int sa0 = sw(ty * TM + 0), sa1 = sw(ty * TM + 4);
    int sa2 = sw(ty * TM + 8), sa3 = sw(ty * TM + 12);
    int sb0 = sw(tx * TN + 0), sb1 = sw(tx * TN + 4);

    for (int k0 = 0; k0 < KD; k0 += BK) {
        float4 a0 = *(const float4*)(Arow + k0 + 0);
        float4 a1 = *(const float4*)(Arow + k0 + 4);
        float4 a2 = *(const float4*)(Arow + k0 + 8);
        float4 a3 = *(const float4*)(Arow + k0 + 12);
        float4 b0 = *(const float4*)(Brow + k0 + 0);
        float4 b1 = *(const float4*)(Brow + k0 + 4);
        float4 b2 = *(const float4*)(Brow + k0 + 8);
        float4 b3 = *(const float4*)(Brow + k0 + 12);
        __syncthreads();
        As[0][stid] = a0.x;  As[1][stid] = a0.y;  As[2][stid] = a0.z;  As[3][stid] = a0.w;
        As[4][stid] = a1.x;  As[5][stid] = a1.y;  As[6][stid] = a1.z;  As[7][stid] = a1.w;
        As[8][stid] = a2.x;  As[9][stid] = a2.y;  As[10][stid] = a2.z; As[11][stid] = a2.w;
        As[12][stid] = a3.x; As[13][stid] = a3.y; As[14][stid] = a3.z; As[15][stid] = a3.w;
        Bs[0][stid] = b0.x;  Bs[1][stid] = b0.y;  Bs[2][stid] = b0.z;  Bs[3][stid] = b0.w;
        Bs[4][stid] = b1.x;  Bs[5][stid] = b1.y;  Bs[6][stid] = b1.z;  Bs[7][stid] = b1.w;
        Bs[8][stid] = b2.x;  Bs[9][stid] = b2.y;  Bs[10][stid] = b2.z; Bs[11][stid] = b2.w;
        Bs[12][stid] = b3.x; Bs[13][stid] = b3.y; Bs[14][stid] = b3.z; Bs[15][stid] = b3.w;
        __syncthreads();
#pragma unroll
        for (int k = 0; k < BK; k++) {
            float4 va0 = *(const float4*)&As[k][sa0];
            float4 va1 = *(const float4*)&As[k][sa1];
            float4 va2 = *(const float4*)&As[k][sa2];
            float4 va3 = *(const float4*)&As[k][sa3];
            float4 vb0 = *(const float4*)&Bs[k][sb0];
            float4 vb1 = *(const float4*)&Bs[k][sb1];
            float av[TM] = {va0.x, va0.y, va0.z, va0.w, va1.x, va1.y, va1.z, va1.w,
                            va2.x, va2.y, va2.z, va2.w, va3.x, va3.y, va3.z, va3.w};
            float bv[TN] = {vb0.x, vb0.y, vb0.z, vb0.w, vb1.x, vb1.y, vb1.z, vb1.w};
#pragma unroll
            for (int i = 0; i < TM; i++)
#pragma unroll
                for (int j = 0; j < TN; j++)
                    acc[i][j] = fmaf(av[i], bv[j], acc[i][j]);
        }
    }

    // ---- epilogue: R = num/denom in-place, direct store, row stats ----
    float sqi[TM], sqj[TN];
#pragma unroll
    for (int i = 0; i < TM; i++) sqi[i] = sq[row0 + ty * TM + i];
#pragma unroll
    for (int j = 0; j < TN; j++) sqj[j] = sq[col0 + tx * TN + j];

#pragma unroll
    for (int i = 0; i < TM; i++) {
        double rs_ = 0.0, ps_ = 0.0;
        float pc_ = 0.0f, nc_ = 0.0f;
#pragma unroll
        for (int j = 0; j < TN; j++) {
            float denom = sqrtf(sqi[i] * sqj[j] + 1e-10f);
            float r = acc[i][j] / denom;        // IEEE div, matches np
            acc[i][j] = r;
            rs_ += (double)r;
            if (r > 0.0f) { ps_ += (double)r; pc_ += 1.0f; }
            else if (r < 0.0f) { nc_ += 1.0f; }
        }
        size_t obase = (((size_t)(row0 + ty * TM + i)) << 13) + col0 + tx * TN;
        if (f) {
            float* O = (float*)outv;
            *(float4*)(O + obase)     = make_float4(acc[i][0], acc[i][1], acc[i][2], acc[i][3]);
            *(float4*)(O + obase + 4) = make_float4(acc[i][4], acc[i][5], acc[i][6], acc[i][7]);
        } else {
            union { uint4 u; ushort16 s[8]; } pk;
#pragma unroll
            for (int j = 0; j < TN; j++) pk.s[j] = f2bf(acc[i][j]);
            *(uint4*)((__hip_bfloat16*)outv + obase) = pk.u;
        }
        for (int off = 1; off < 16; off <<= 1) {
            rs_ += __shfl_xor(rs_, off);
            ps_ += __shfl_xor(ps_, off);
            pc_ += __shfl_xor(pc_, off);
            nc_ += __shfl_xor(nc_, off);
        }
        if (tx == 0) {
            int gr = row0 + ty * TM + i;
            atomicAdd(&rowsum[gr], rs_);
            atomicAdd(&possum[gr], ps_);
            atomicAdd(&poscnt[gr], (double)pc_);
            atomicAdd(&negcnt[gr], (double)nc_);
        }
    }

    // ---- mirror tile (off-diagonal only): transposed store + column stats ----
    if (bx != by) {
        int l = tid & 63, w = tid >> 6;
#pragma unroll
        for (int j = 0; j < TN; j++) {
            size_t mbase = (((size_t)(col0 + tx * TN + j)) << 13) + row0 + ty * TM;
            if (f) {
                float* O = (float*)outv;
                *(float4*)(O + mbase + 0)  = make_float4(acc[0][j], acc[1][j], acc[2][j], acc[3][j]);
                *(float4*)(O + mbase + 4)  = make_float4(acc[4][j], acc[5][j], acc[6][j], acc[7][j]);
                *(float4*)(O + mbase + 8)  = make_float4(acc[8][j], acc[9][j], acc[10][j], acc[11][j]);
                *(float4*)(O + mbase + 12) = make_float4(acc[12][j], acc[13][j], acc[14][j], acc[15][j]);
            } else {
                union { uint4 u; ushort16 s[8]; } pk0, pk1;
#pragma unroll
                for (int i = 0; i < 8; i++) pk0.s[i] = f2bf(acc[i][j]);
#pragma unroll
                for (int i = 0; i < 8; i++) pk1.s[i] = f2bf(acc[8 + i][j]);
                *(uint4*)((__hip_bfloat16*)outv + mbase) = pk0.u;
                *(uint4*)((__hip_bfloat16*)outv + mbase + 8) = pk1.u;
            }
            double cs = 0.0, cp = 0.0;
            float cc = 0.0f, cn = 0.0f;
#pragma unroll
            for (int i = 0; i < TM; i++) {
                float r = acc[i][j];
                cs += (double)r;
                if (r > 0.0f) { cp += (double)r; cc += 1.0f; }
                else if (r < 0.0f) { cn += 1.0f; }
            }
            // reduce over ty groups within the wave (lanes differ by 16, 32)
            cs += __shfl_xor(cs, 16); cs += __shfl_xor(cs, 32);
            cp += __shfl_xor(cp, 16); cp += __shfl_xor(cp, 32);
            cc += __shfl_xor(cc, 16); cc += __shfl_xor(cc, 32);
            cn += __shfl_xor(cn, 16); cn += __shfl_xor(cn, 32);
            if (l < 16) {
                int c = tx * TN + j;   // tx == l here
                scratch[w][0][c] = cs;
                scratch[w][1][c] = cp;
                scratch[w][2][c] = (double)cc;
                scratch[w][3][c] = (double)cn;
            }
        }
        __syncthreads();
        if (tid < BN) {
            int gc = col0 + tid;
            double cs = scratch[0][0][tid] + scratch[1][0][tid];
            double cp = scratch[0][1][tid] + scratch[1][1][tid];
            double cc = scratch[0][2][tid] + scratch[1][2][tid];
            double cn = scratch[0][3][tid] + scratch[1][3][tid];
            atomicAdd(&rowsum[gc], cs);
            atomicAdd(&possum[gc], cp);
            atomicAdd(&poscnt[gc], cc);
            atomicAdd(&negcnt[gc], cn);
        }
    }
}

// ---------------- K3: per-row finalize + global positive stats ----------------
__global__ void rowfin_kernel(const double* __restrict__ rowsum, const double* __restrict__ possum,
                              const double* __restrict__ poscnt, const double* __restrict__ negcnt,
                              float* __restrict__ inv_rs, double* __restrict__ gstats) {
    __shared__ double sc[256], sn[256];
    int n = blockIdx.x * 256 + threadIdx.x;
    double rsumv = rowsum[n];
    double rs = rsumv + 1e-10;
    inv_rs[n] = (float)(1.0 / rs);
    double contrib, cnt;
    if (rs > 0.0) { contrib = possum[n] / rs; cnt = poscnt[n]; }
    else          { contrib = (rsumv - possum[n]) / rs; cnt = negcnt[n]; }
    sc[threadIdx.x] = contrib; sn[threadIdx.x] = cnt;
    __syncthreads();
    for (int s = 128; s > 0; s >>= 1) {
        if (threadIdx.x < s) { sc[threadIdx.x] += sc[threadIdx.x + s]; sn[threadIdx.x] += sn[threadIdx.x + s]; }
        __syncthreads();
    }
    if (threadIdx.x == 0) { atomicAdd(&gstats[0], sc[0]); atomicAdd(&gstats[1], sn[0]); }
}

// ---------------- K3b: tau ----------------
__global__ void tau_kernel(const double* __restrict__ gstats, float* __restrict__ tau) {
    double cnt = gstats[1];
    if (cnt < 1.0) cnt = 1.0;
    double mp = gstats[0] / cnt;
    tau[0] = (mp > 0.0) ? (float)mp : 1.0f;   // TAU_FACTOR = 1.0
}

// ---------------- K4: R' = R*inv_rs, threshold, in-place on d_out ----------------
__global__ void thresh_kernel(void* __restrict__ R_,
                              const float* __restrict__ inv_rs,
                              const float* __restrict__ tau_p,
                              const int* __restrict__ flag) {
    int f = *flag;
    float tau = *tau_p;
    size_t base = ((size_t)blockIdx.x * 256 + threadIdx.x) * 8;
    if (base >= (size_t)NN * NN) return;
    float inv = inv_rs[base >> 13];
    if (f) {
        float* R = (float*)R_;
        float4 v0 = *(float4*)(R + base);
        float4 v1 = *(float4*)(R + base + 4);
        float vv[8] = {v0.x, v0.y, v0.z, v0.w, v1.x, v1.y, v1.z, v1.w};
#pragma unroll
        for (int t = 0; t < 8; t++) {
            float val = vv[t] * inv;
            vv[t] = (val >= tau) ? val : 0.0f;
        }
        *(float4*)(R + base)     = make_float4(vv[0], vv[1], vv[2], vv[3]);
        *(float4*)(R + base + 4) = make_float4(vv[4], vv[5], vv[6], vv[7]);
    } else {
        __hip_bfloat16* R = (__hip_bfloat16*)R_;
        union { uint4 u; ushort16 s[8]; } in, out;
        in.u = *(const uint4*)(R + base);
#pragma unroll
        for (int t = 0; t < 8; t++) {
            float val = bf2f(in.s[t]) * inv;
            float r = (val >= tau) ? val : 0.0f;
            out.s[t] = f2bf(r);
        }
        *(uint4*)(R + base) = out.u;
    }
}

// ---------------- sentinel: ws too small -> unmistakable absmax signature ----------------
__global__ void sentinel_kernel(uint32* __restrict__ out, size_t n32) {
    size_t i = (size_t)blockIdx.x * 256 + threadIdx.x;
    if (i < n32) out[i] = 0x47C35000u;
}

extern "C" void kernel_launch(void* const* d_in, const int* in_sizes, int n_in,
                              void* d_out, int out_size, void* d_ws, size_t ws_size,
                              hipStream_t stream) {
    const void* P = d_in[0];
    const void* A = d_in[1];

    char* ws = (char*)d_ws;
    size_t off = 0;
    float* X = (float*)(ws + off);        off += (size_t)NN * KD * 4;   // 16 MB
    float* sqv = (float*)(ws + off);      off += (size_t)NN * 4;
    double* rowsum = (double*)(ws + off); off += (size_t)NN * 8;
    double* possum = (double*)(ws + off); off += (size_t)NN * 8;
    double* poscnt = (double*)(ws + off); off += (size_t)NN * 8;
    double* negcnt = (double*)(ws + off); off += (size_t)NN * 8;
    float* inv_rs = (float*)(ws + off);   off += (size_t)NN * 4;
    double* gstats = (double*)(ws + off); off += 16;
    float* tau = (float*)(ws + off);      off += 16;
    int* flag = (int*)(ws + off);         off += 16;

    if (ws_size < off) {
        size_t n32 = ((size_t)out_size * 2) / 4;
        sentinel_kernel<<<(int)((n32 + 255) / 256), 256, 0, stream>>>((uint32*)d_out, n32);
        return;
    }

    detect_kernel<<<1, 256, 0, stream>>>((const uint32*)A, flag);
    init_kernel<<<(4 * NN + 255) / 256, 256, 0, stream>>>(rowsum, gstats);
    prep_kernel<<<NN / 4, 256, 0, stream>>>(P, A, flag, X, sqv);
    dim3 ggrid(NN / BN, NN / BM);
    gemm_kernel<<<ggrid, 128, 0, stream>>>(X, sqv, d_out, flag, rowsum, possum, poscnt, negcnt);
    rowfin_kernel<<<NN / 256, 256, 0, stream>>>(rowsum, possum, poscnt, negcnt, inv_rs, gstats);
    tau_kernel<<<1, 1, 0, stream>>>(gstats, tau);
    thresh_kernel<<<(int)(((size_t)NN * NN / 8 + 255) / 256), 256, 0, stream>>>(d_out, inv_rs, tau, flag);
}

// Round 4
// 1045.759 us; speedup vs baseline: 1.1805x; 1.1805x over previous
//
#include <hip/hip_runtime.h>
#include <hip/hip_bf16.h>

#define NN 8192
#define KF 256
#define KD 512
#define CK 32

typedef unsigned int uint32;
typedef unsigned short ushort16;

static __device__ __forceinline__ float bf2f(ushort16 u) {
    union { uint32 i; float f; } v; v.i = ((uint32)u) << 16; return v.f;
}
static __device__ __forceinline__ ushort16 f2bf(float f) {
    __hip_bfloat16 h = __float2bfloat16(f);  // RNE
    union { __hip_bfloat16 h; ushort16 u; } v; v.h = h; return v.u;
}

// ---------------- K-1: detect input dtype ----------------
__global__ void detect_kernel(const uint32* __restrict__ rawA, int* __restrict__ flag) {
    __shared__ int s_top2, s_nz;
    if (threadIdx.x == 0) { s_top2 = 0; s_nz = 0; }
    __syncthreads();
    int top2 = 0, nz = 0;
    for (int i = threadIdx.x; i < 4096; i += 256) {
        uint32 lo = rawA[i] & 0xFFFFu;
        if (lo & 0xC000u) top2 = 1;
        if (lo) nz = 1;
    }
    if (top2) atomicOr(&s_top2, 1);
    if (nz) atomicOr(&s_nz, 1);
    __syncthreads();
    if (threadIdx.x == 0) {
        int f;
        if (s_top2) f = 1;        // true fp32
        else if (s_nz) f = 0;     // bf16 storage
        else f = 1;               // fp32 holding bf16-rounded values
        *flag = f;
    }
}

// ---------------- K0: zero accumulators ----------------
__global__ void init_kernel(double* acc, double* gstats) {
    int i = blockIdx.x * 256 + threadIdx.x;
    if (i < 4 * NN) acc[i] = 0.0;
    if (i < 2) gstats[i] = 0.0;
}

// ---------------- K1: top-32 mask + build X = [Ac | As] (fp32) + sq ----------------
__global__ void prep_kernel(const void* __restrict__ P_, const void* __restrict__ A_,
                            const int* __restrict__ flag,
                            float* __restrict__ X, float* __restrict__ sq) {
    int f = *flag;
    int row = blockIdx.x * 4 + (threadIdx.x >> 6);
    int lane = threadIdx.x & 63;
    if (row >= NN) return;
    float a[4], p[4];
    bool sel[4] = {false, false, false, false};
    if (f) {
        const float* Ar = (const float*)A_ + (size_t)row * KF;
        const float* Pr = (const float*)P_ + (size_t)row * KF;
#pragma unroll
        for (int j = 0; j < 4; j++) {
            int k = lane + 64 * j;
            a[j] = Ar[k];
            p[j] = Pr[k];
        }
    } else {
        const __hip_bfloat16* Ar = (const __hip_bfloat16*)A_ + (size_t)row * KF;
        const __hip_bfloat16* Pr = (const __hip_bfloat16*)P_ + (size_t)row * KF;
#pragma unroll
        for (int j = 0; j < 4; j++) {
            int k = lane + 64 * j;
            a[j] = __bfloat162float(Ar[k]);
            p[j] = __bfloat162float(Pr[k]);
        }
    }
    for (int it = 0; it < CK; ++it) {
        float bv = -1.0f; int bi = KF;
#pragma unroll
        for (int j = 0; j < 4; j++) {
            int k = lane + 64 * j;
            if (!sel[j] && (a[j] > bv || (a[j] == bv && k < bi))) { bv = a[j]; bi = k; }
        }
        for (int off = 32; off > 0; off >>= 1) {
            float ov = __shfl_xor(bv, off);
            int   oi = __shfl_xor(bi, off);
            if (ov > bv || (ov == bv && oi < bi)) { bv = ov; bi = oi; }
        }
        if ((bi & 63) == lane) sel[bi >> 6] = true;
    }
    double sq_part = 0.0;
    float* Xr = X + (size_t)row * KD;
#pragma unroll
    for (int j = 0; j < 4; j++) {
        int k = lane + 64 * j;
        float c = 0.0f, s = 0.0f;
        if (sel[j]) {
            c = a[j] * cosf(p[j]);
            s = a[j] * sinf(p[j]);
            sq_part += (double)a[j] * (double)a[j];
        }
        Xr[k] = c;
        Xr[KF + k] = s;
    }
    for (int off = 32; off > 0; off >>= 1) sq_part += __shfl_xor(sq_part, off);
    if (lane == 0) sq[row] = (float)sq_part;
}

// ---------------- K2: symmetric fp32 GEMM, 128x128 tile, 256 thr, TM8xTN8 ----------------
#define BM 128
#define BN 128
#define BK 16
#define TM 8
#define TN 8
#define LDP 140   // swizzled physical row length: sw(127)=139 -> 140

static __device__ __forceinline__ int sw(int c) { return c + ((c >> 5) << 2); }

__global__ __launch_bounds__(256)
void gemm_kernel(const float* __restrict__ X, const float* __restrict__ sq,
                 void* __restrict__ outv, const int* __restrict__ flag,
                 double* __restrict__ rowsum, double* __restrict__ possum,
                 double* __restrict__ poscnt, double* __restrict__ negcnt) {
    int bx = blockIdx.x, by = blockIdx.y;
    if (bx < by) return;                    // upper-triangle tiles only
    __shared__ float As[BK][LDP];
    __shared__ float Bs[BK][LDP];
    __shared__ double scratch[4][4][BN];
    int f = *flag;
    int tid = threadIdx.x;
    int tx = tid & 15;        // col group (TN=8)
    int ty = tid >> 4;        // row group (TM=8)
    int row0 = by * BM, col0 = bx * BN;

    float acc[TM][TN] = {};

    // staging: each thread loads 8 floats of A-tile and 8 of B-tile
    int lr = tid >> 1;            // 0..127
    int lk = (tid & 1) * 8;       // 0 or 8
    int slr = sw(lr);
    const float* Arow = X + (size_t)(row0 + lr) * KD + lk;
    const float* Brow = X + (size_t)(col0 + lr) * KD + lk;
    int sa0 = sw(ty * TM + 0), sa1 = sw(ty * TM + 4);
    int sb0 = sw(tx * TN + 0), sb1 = sw(tx * TN + 4);

    for (int k0 = 0; k0 < KD; k0 += BK) {
        float4 a0 = *(const float4*)(Arow + k0 + 0);
        float4 a1 = *(const float4*)(Arow + k0 + 4);
        float4 b0 = *(const float4*)(Brow + k0 + 0);
        float4 b1 = *(const float4*)(Brow + k0 + 4);
        __syncthreads();
        As[lk + 0][slr] = a0.x; As[lk + 1][slr] = a0.y; As[lk + 2][slr] = a0.z; As[lk + 3][slr] = a0.w;
        As[lk + 4][slr] = a1.x; As[lk + 5][slr] = a1.y; As[lk + 6][slr] = a1.z; As[lk + 7][slr] = a1.w;
        Bs[lk + 0][slr] = b0.x; Bs[lk + 1][slr] = b0.y; Bs[lk + 2][slr] = b0.z; Bs[lk + 3][slr] = b0.w;
        Bs[lk + 4][slr] = b1.x; Bs[lk + 5][slr] = b1.y; Bs[lk + 6][slr] = b1.z; Bs[lk + 7][slr] = b1.w;
        __syncthreads();
#pragma unroll
        for (int k = 0; k < BK; k++) {
            float4 va0 = *(const float4*)&As[k][sa0];
            float4 va1 = *(const float4*)&As[k][sa1];
            float4 vb0 = *(const float4*)&Bs[k][sb0];
            float4 vb1 = *(const float4*)&Bs[k][sb1];
            float av[TM] = {va0.x, va0.y, va0.z, va0.w, va1.x, va1.y, va1.z, va1.w};
            float bv[TN] = {vb0.x, vb0.y, vb0.z, vb0.w, vb1.x, vb1.y, vb1.z, vb1.w};
#pragma unroll
            for (int i = 0; i < TM; i++)
#pragma unroll
                for (int j = 0; j < TN; j++)
                    acc[i][j] = fmaf(av[i], bv[j], acc[i][j]);
        }
    }

    // ---- epilogue: R = num/denom in-place, direct store, row stats ----
    float sqi[TM], sqj[TN];
#pragma unroll
    for (int i = 0; i < TM; i++) sqi[i] = sq[row0 + ty * TM + i];
#pragma unroll
    for (int j = 0; j < TN; j++) sqj[j] = sq[col0 + tx * TN + j];

#pragma unroll
    for (int i = 0; i < TM; i++) {
        double rs_ = 0.0, ps_ = 0.0;
        float pc_ = 0.0f, nc_ = 0.0f;
#pragma unroll
        for (int j = 0; j < TN; j++) {
            float denom = sqrtf(sqi[i] * sqj[j] + 1e-10f);
            float r = acc[i][j] / denom;        // IEEE div, matches np
            acc[i][j] = r;
            rs_ += (double)r;
            if (r > 0.0f) { ps_ += (double)r; pc_ += 1.0f; }
            else if (r < 0.0f) { nc_ += 1.0f; }
        }
        size_t obase = (((size_t)(row0 + ty * TM + i)) << 13) + col0 + tx * TN;
        if (f) {
            float* O = (float*)outv;
            *(float4*)(O + obase)     = make_float4(acc[i][0], acc[i][1], acc[i][2], acc[i][3]);
            *(float4*)(O + obase + 4) = make_float4(acc[i][4], acc[i][5], acc[i][6], acc[i][7]);
        } else {
            union { uint4 u; ushort16 s[8]; } pk;
#pragma unroll
            for (int j = 0; j < TN; j++) pk.s[j] = f2bf(acc[i][j]);
            *(uint4*)((__hip_bfloat16*)outv + obase) = pk.u;
        }
        for (int off = 1; off < 16; off <<= 1) {
            rs_ += __shfl_xor(rs_, off);
            ps_ += __shfl_xor(ps_, off);
            pc_ += __shfl_xor(pc_, off);
            nc_ += __shfl_xor(nc_, off);
        }
        if (tx == 0) {
            int gr = row0 + ty * TM + i;
            atomicAdd(&rowsum[gr], rs_);
            atomicAdd(&possum[gr], ps_);
            atomicAdd(&poscnt[gr], (double)pc_);
            atomicAdd(&negcnt[gr], (double)nc_);
        }
    }

    // ---- mirror tile (off-diagonal only): transposed store + column stats ----
    if (bx != by) {
        int l = tid & 63, w = tid >> 6;
#pragma unroll
        for (int j = 0; j < TN; j++) {
            size_t mbase = (((size_t)(col0 + tx * TN + j)) << 13) + row0 + ty * TM;
            if (f) {
                float* O = (float*)outv;
                *(float4*)(O + mbase + 0) = make_float4(acc[0][j], acc[1][j], acc[2][j], acc[3][j]);
                *(float4*)(O + mbase + 4) = make_float4(acc[4][j], acc[5][j], acc[6][j], acc[7][j]);
            } else {
                union { uint4 u; ushort16 s[8]; } pk;
#pragma unroll
                for (int i = 0; i < 8; i++) pk.s[i] = f2bf(acc[i][j]);
                *(uint4*)((__hip_bfloat16*)outv + mbase) = pk.u;
            }
            double cs = 0.0, cp = 0.0;
            float cc = 0.0f, cn = 0.0f;
#pragma unroll
            for (int i = 0; i < TM; i++) {
                float r = acc[i][j];
                cs += (double)r;
                if (r > 0.0f) { cp += (double)r; cc += 1.0f; }
                else if (r < 0.0f) { cn += 1.0f; }
            }
            // reduce over the 4 ty-groups within this wave (lane bits 4,5)
            cs += __shfl_xor(cs, 16); cs += __shfl_xor(cs, 32);
            cp += __shfl_xor(cp, 16); cp += __shfl_xor(cp, 32);
            cc += __shfl_xor(cc, 16); cc += __shfl_xor(cc, 32);
            cn += __shfl_xor(cn, 16); cn += __shfl_xor(cn, 32);
            if (l < 16) {
                int c = tx * TN + j;   // tx == l here
                scratch[w][0][c] = cs;
                scratch[w][1][c] = cp;
                scratch[w][2][c] = (double)cc;
                scratch[w][3][c] = (double)cn;
            }
        }
        __syncthreads();
        if (tid < BN) {
            int gc = col0 + tid;
            double cs = 0.0, cp = 0.0, cc = 0.0, cn = 0.0;
#pragma unroll
            for (int ww = 0; ww < 4; ww++) {
                cs += scratch[ww][0][tid];
                cp += scratch[ww][1][tid];
                cc += scratch[ww][2][tid];
                cn += scratch[ww][3][tid];
            }
            atomicAdd(&rowsum[gc], cs);
            atomicAdd(&possum[gc], cp);
            atomicAdd(&poscnt[gc], cc);
            atomicAdd(&negcnt[gc], cn);
        }
    }
}

// ---------------- K3: per-row finalize + global positive stats ----------------
__global__ void rowfin_kernel(const double* __restrict__ rowsum, const double* __restrict__ possum,
                              const double* __restrict__ poscnt, const double* __restrict__ negcnt,
                              float* __restrict__ inv_rs, double* __restrict__ gstats) {
    __shared__ double sc[256], sn[256];
    int n = blockIdx.x * 256 + threadIdx.x;
    double rsumv = rowsum[n];
    double rs = rsumv + 1e-10;
    inv_rs[n] = (float)(1.0 / rs);
    double contrib, cnt;
    if (rs > 0.0) { contrib = possum[n] / rs; cnt = poscnt[n]; }
    else          { contrib = (rsumv - possum[n]) / rs; cnt = negcnt[n]; }
    sc[threadIdx.x] = contrib; sn[threadIdx.x] = cnt;
    __syncthreads();
    for (int s = 128; s > 0; s >>= 1) {
        if (threadIdx.x < s) { sc[threadIdx.x] += sc[threadIdx.x + s]; sn[threadIdx.x] += sn[threadIdx.x + s]; }
        __syncthreads();
    }
    if (threadIdx.x == 0) { atomicAdd(&gstats[0], sc[0]); atomicAdd(&gstats[1], sn[0]); }
}

// ---------------- K3b: tau ----------------
__global__ void tau_kernel(const double* __restrict__ gstats, float* __restrict__ tau) {
    double cnt = gstats[1];
    if (cnt < 1.0) cnt = 1.0;
    double mp = gstats[0] / cnt;
    tau[0] = (mp > 0.0) ? (float)mp : 1.0f;   // TAU_FACTOR = 1.0
}

// ---------------- K4: R' = R*inv_rs, threshold, in-place on d_out ----------------
__global__ void thresh_kernel(void* __restrict__ R_,
                              const float* __restrict__ inv_rs,
                              const float* __restrict__ tau_p,
                              const int* __restrict__ flag) {
    int f = *flag;
    float tau = *tau_p;
    size_t base = ((size_t)blockIdx.x * 256 + threadIdx.x) * 8;
    if (base >= (size_t)NN * NN) return;
    float inv = inv_rs[base >> 13];
    if (f) {
        float* R = (float*)R_;
        float4 v0 = *(float4*)(R + base);
        float4 v1 = *(float4*)(R + base + 4);
        float vv[8] = {v0.x, v0.y, v0.z, v0.w, v1.x, v1.y, v1.z, v1.w};
#pragma unroll
        for (int t = 0; t < 8; t++) {
            float val = vv[t] * inv;
            vv[t] = (val >= tau) ? val : 0.0f;
        }
        *(float4*)(R + base)     = make_float4(vv[0], vv[1], vv[2], vv[3]);
        *(float4*)(R + base + 4) = make_float4(vv[4], vv[5], vv[6], vv[7]);
    } else {
        __hip_bfloat16* R = (__hip_bfloat16*)R_;
        union { uint4 u; ushort16 s[8]; } in, out;
        in.u = *(const uint4*)(R + base);
#pragma unroll
        for (int t = 0; t < 8; t++) {
            float val = bf2f(in.s[t]) * inv;
            float r = (val >= tau) ? val : 0.0f;
            out.s[t] = f2bf(r);
        }
        *(uint4*)(R + base) = out.u;
    }
}

// ---------------- sentinel: ws too small -> unmistakable absmax signature ----------------
__global__ void sentinel_kernel(uint32* __restrict__ out, size_t n32) {
    size_t i = (size_t)blockIdx.x * 256 + threadIdx.x;
    if (i < n32) out[i] = 0x47C35000u;
}

extern "C" void kernel_launch(void* const* d_in, const int* in_sizes, int n_in,
                              void* d_out, int out_size, void* d_ws, size_t ws_size,
                              hipStream_t stream) {
    const void* P = d_in[0];
    const void* A = d_in[1];

    char* ws = (char*)d_ws;
    size_t off = 0;
    float* X = (float*)(ws + off);        off += (size_t)NN * KD * 4;   // 16 MB
    float* sqv = (float*)(ws + off);      off += (size_t)NN * 4;
    double* rowsum = (double*)(ws + off); off += (size_t)NN * 8;
    double* possum = (double*)(ws + off); off += (size_t)NN * 8;
    double* poscnt = (double*)(ws + off); off += (size_t)NN * 8;
    double* negcnt = (double*)(ws + off); off += (size_t)NN * 8;
    float* inv_rs = (float*)(ws + off);   off += (size_t)NN * 4;
    double* gstats = (double*)(ws + off); off += 16;
    float* tau = (float*)(ws + off);      off += 16;
    int* flag = (int*)(ws + off);         off += 16;

    if (ws_size < off) {
        size_t n32 = ((size_t)out_size * 2) / 4;
        sentinel_kernel<<<(int)((n32 + 255) / 256), 256, 0, stream>>>((uint32*)d_out, n32);
        return;
    }

    detect_kernel<<<1, 256, 0, stream>>>((const uint32*)A, flag);
    init_kernel<<<(4 * NN + 255) / 256, 256, 0, stream>>>(rowsum, gstats);
    prep_kernel<<<NN / 4, 256, 0, stream>>>(P, A, flag, X, sqv);
    dim3 ggrid(NN / BN, NN / BM);
    gemm_kernel<<<ggrid, 256, 0, stream>>>(X, sqv, d_out, flag, rowsum, possum, poscnt, negcnt);
    rowfin_kernel<<<NN / 256, 256, 0, stream>>>(rowsum, possum, poscnt, negcnt, inv_rs, gstats);
    tau_kernel<<<1, 1, 0, stream>>>(gstats, tau);
    thresh_kernel<<<(int)(((size_t)NN * NN / 8 + 255) / 256), 256, 0, stream>>>(d_out, inv_rs, tau, flag);
}